// Round 7
// baseline (325.233 us; speedup 1.0000x reference)
//
#include <hip/hip_runtime.h>
#include <math.h>

typedef __attribute__((ext_vector_type(4))) float floatx4;
typedef __attribute__((ext_vector_type(8))) short shortx8;

#define M_TILE 128
#define N_TILE 64
#define BK 64

__device__ __forceinline__ unsigned short f2bf(float f) {
    union { float f; unsigned int u; } v; v.f = f;
    unsigned int r = v.u + 0x7fffu + ((v.u >> 16) & 1u);   // RNE
    return (unsigned short)(r >> 16);
}
__device__ __forceinline__ float bf2f(unsigned short u) {
    union { unsigned int u; float f; } v; v.u = ((unsigned int)u) << 16;
    return v.f;
}
__device__ __forceinline__ void gload_lds16(const unsigned short* g, unsigned short* l) {
    __builtin_amdgcn_global_load_lds(
        (const __attribute__((address_space(1))) void*)g,
        (__attribute__((address_space(3))) void*)l, 16, 0, 0);
}

// ---------- single preprocessing kernel: cvt X,H + transpose-cvt W,R ----------
__global__ void prep_kernel(const float* __restrict__ X, const float* __restrict__ H,
                            const float* __restrict__ W, const float* __restrict__ R,
                            unsigned short* __restrict__ Xb, unsigned short* __restrict__ Hb,
                            unsigned short* __restrict__ Wt, unsigned short* __restrict__ Rt)
{
    const int bid = blockIdx.x;
    const int tx  = threadIdx.x;
    if (bid < 16384) {
        const float* src = (bid < 8192) ? X : H;
        unsigned short* dst = (bid < 8192) ? Xb : Hb;
        const int i = (bid & 8191) * 256 + tx;         // float4 index (8192 IS pow2)
        float4 v = ((const float4*)src)[i];
        ushort4 s;
        s.x = f2bf(v.x); s.y = f2bf(v.y); s.z = f2bf(v.z); s.w = f2bf(v.w);
        ((ushort4*)dst)[i] = s;
        return;
    }
    __shared__ float tile[64][66];
    const int tb = bid - 16384;
    const float* src = (tb < 768) ? W : R;
    unsigned short* dst = (tb < 768) ? Wt : Rt;
    const int tt = (tb < 768) ? tb : tb - 768;         // 768 is not pow2 — no masking!
    const int col0 = (tt % 48) * 64;
    const int k0   = (tt / 48) * 64;
    const int n4 = tx & 15, kl = tx >> 4;
    #pragma unroll
    for (int i = 0; i < 4; ++i) {
        const int k = kl + i * 16;
        float4 v = *(const float4*)(src + (size_t)(k0 + k) * 3072 + col0 + n4 * 4);
        tile[k][n4 * 4 + 0] = v.x; tile[k][n4 * 4 + 1] = v.y;
        tile[k][n4 * 4 + 2] = v.z; tile[k][n4 * 4 + 3] = v.w;
    }
    __syncthreads();
    #pragma unroll
    for (int i = 0; i < 2; ++i) {
        const int c  = tx + i * 256;
        const int nl = c >> 3, kc = c & 7;
        ushort4 s0, s1;
        s0.x = f2bf(tile[kc*8+0][nl]); s0.y = f2bf(tile[kc*8+1][nl]);
        s0.z = f2bf(tile[kc*8+2][nl]); s0.w = f2bf(tile[kc*8+3][nl]);
        s1.x = f2bf(tile[kc*8+4][nl]); s1.y = f2bf(tile[kc*8+5][nl]);
        s1.z = f2bf(tile[kc*8+6][nl]); s1.w = f2bf(tile[kc*8+7][nl]);
        unsigned short* p = dst + (size_t)(col0 + nl) * 1024 + k0 + kc * 8;
        *(ushort4*)p = s0;
        *(ushort4*)(p + 4) = s1;
    }
}

// ---------------- main fused GEMM kernel ----------------
// A: double-buffered LDS (global_load_lds, XOR bank swizzle, conflicts=0 verified).
// B: NO LDS — each lane's B-fragment is a direct 16B global load from the
//    [n][k] weight layout, consumed by MFMA with compiler-managed vmcnt
//    (AITER-style MFMA<->buffer_load interleave). LDS traffic -60%.
__global__ __launch_bounds__(256, 2)
void gru_mfma_kernel(const unsigned short* __restrict__ Xb,   // [8192][1024] bf16
                     const unsigned short* __restrict__ Hb,   // [8192][1024] bf16
                     const unsigned short* __restrict__ Wt,   // [3072][1024] bf16 (W^T)
                     const unsigned short* __restrict__ Rt,   // [3072][1024] bf16 (R^T)
                     const float* __restrict__ bias,          // [2][3072]
                     float* __restrict__ out)
{
    __shared__ __attribute__((aligned(16))) unsigned short ldsA[2][2][M_TILE * BK]; // 64 KB dbuf

    const int tid  = threadIdx.x;
    const int bid  = blockIdx.x;
    const int bn   = bid & 15;        // XCD swizzle: weight slice resident in one XCD's L2
    const int bm   = bid >> 4;
    const int m0   = bm * M_TILE;
    const int n0   = bn * N_TILE;

    const int wid  = tid >> 6;
    const int lane = tid & 63;
    const int wr   = wid >> 1;
    const int wc   = wid & 1;
    const int lo   = lane & 15;
    const int quad = lane >> 4;
    const int lx   = lane & 7;

    // A staging: 8-row segments; lane fetches XOR-permuted k-chunk (deposit is
    // lane-ordered regardless of address order — HW-verified rounds 3/4/6)
    const int lrow = lane >> 3;
    const int lkc  = (lane & 7) ^ lrow;

    // B base pointers: row (n0+wc*32+j*16+lo), k contiguous
    const int ncol = n0 + wc * 32 + lo;
    const unsigned short* pWz = Wt + (size_t)(       ncol) * 1024;
    const unsigned short* pWr = Wt + (size_t)(1024 + ncol) * 1024;
    const unsigned short* pWh = Wt + (size_t)(2048 + ncol) * 1024;
    const unsigned short* pRz = Rt + (size_t)(       ncol) * 1024;
    const unsigned short* pRr = Rt + (size_t)(1024 + ncol) * 1024;
    const unsigned short* pRh = Rt + (size_t)(2048 + ncol) * 1024;

    floatx4 acc_z[4][2]  = {};
    floatx4 acc_r[4][2]  = {};
    floatx4 acc_xh[4][2] = {};
    floatx4 acc_rh[4][2] = {};

    // prologue: stage first A tile into buffer 0
    #pragma unroll
    for (int r = 0; r < 8; ++r) {
        const int seg = r * 4 + wid;
        const int arr = seg >> 4;
        const int s   = seg & 15;
        const size_t gofs = (size_t)(m0 + s * 8 + lrow) * 1024 + lkc * 8;
        gload_lds16(((arr == 0) ? Xb : Hb) + gofs, &ldsA[0][arr][s * 512]);
    }
    __syncthreads();

    int p = 0;
    for (int k0 = 0; k0 < 1024; k0 += BK) {
        // async prefetch next A tile into the other buffer BEFORE the MFMA phase;
        // the barrier's vmcnt(0) drain then lands after ~1k cycles of MFMA.
        if (k0 + BK < 1024) {
            #pragma unroll
            for (int r = 0; r < 8; ++r) {
                const int seg = r * 4 + wid;
                const int arr = seg >> 4;
                const int s   = seg & 15;
                const size_t gofs = (size_t)(m0 + s * 8 + lrow) * 1024 + (k0 + BK) + lkc * 8;
                gload_lds16(((arr == 0) ? Xb : Hb) + gofs, &ldsA[p ^ 1][arr][s * 512]);
            }
        }

        #pragma unroll
        for (int ks = 0; ks < 2; ++ks) {
            const int kcp = ((ks * 4 + quad) ^ lx) * 8;    // un-XOR the A swizzle
            shortx8 a_in[4], a_h[4];
            #pragma unroll
            for (int i = 0; i < 4; ++i) {
                const int row = wr * 64 + i * 16 + lo;
                a_in[i] = *(const shortx8*)&ldsA[p][0][row * BK + kcp];
                a_h[i]  = *(const shortx8*)&ldsA[p][1][row * BK + kcp];
            }
            const size_t ko = (size_t)(k0 + ks * 32 + quad * 8);
            #pragma unroll
            for (int j = 0; j < 2; ++j) {
                const size_t bo = (size_t)j * 16384 + ko;   // j*16 n-rows * 1024
                shortx8 bz  = *(const shortx8*)(pWz + bo);
                shortx8 bre = *(const shortx8*)(pWr + bo);
                shortx8 bh  = *(const shortx8*)(pWh + bo);
                shortx8 rz  = *(const shortx8*)(pRz + bo);
                shortx8 rre = *(const shortx8*)(pRr + bo);
                shortx8 rh  = *(const shortx8*)(pRh + bo);
                #pragma unroll
                for (int i = 0; i < 4; ++i) {
                    acc_z[i][j]  = __builtin_amdgcn_mfma_f32_16x16x32_bf16(a_in[i], bz,  acc_z[i][j],  0, 0, 0);
                    acc_z[i][j]  = __builtin_amdgcn_mfma_f32_16x16x32_bf16(a_h[i],  rz,  acc_z[i][j],  0, 0, 0);
                    acc_r[i][j]  = __builtin_amdgcn_mfma_f32_16x16x32_bf16(a_in[i], bre, acc_r[i][j],  0, 0, 0);
                    acc_r[i][j]  = __builtin_amdgcn_mfma_f32_16x16x32_bf16(a_h[i],  rre, acc_r[i][j],  0, 0, 0);
                    acc_xh[i][j] = __builtin_amdgcn_mfma_f32_16x16x32_bf16(a_in[i], bh,  acc_xh[i][j], 0, 0, 0);
                    acc_rh[i][j] = __builtin_amdgcn_mfma_f32_16x16x32_bf16(a_h[i],  rh,  acc_rh[i][j], 0, 0, 0);
                }
            }
        }
        __syncthreads();
        p ^= 1;
    }

    // epilogue: bias + gates + blend; h_tm1 re-read as bf16
    #pragma unroll
    for (int j = 0; j < 2; ++j) {
        const int col = n0 + wc * 32 + j * 16 + lo;
        const float bz  = bias[col]        + bias[3072 + col];
        const float brr = bias[1024 + col] + bias[4096 + col];
        const float b0h = bias[2048 + col];
        const float b1h = bias[5120 + col];
        #pragma unroll
        for (int i = 0; i < 4; ++i) {
            const int rowb = m0 + wr * 64 + i * 16 + quad * 4;
            #pragma unroll
            for (int r = 0; r < 4; ++r) {
                const int row = rowb + r;
                float sz = acc_z[i][j][r]  + bz;
                float sr = acc_r[i][j][r]  + brr;
                float xh = acc_xh[i][j][r] + b0h;
                float rh = acc_rh[i][j][r] + b1h;
                float z   = fminf(fmaxf(0.2f * sz + 0.5f, 0.0f), 1.0f);
                float rr2 = fminf(fmaxf(0.2f * sr + 0.5f, 0.0f), 1.0f);
                float pre = xh + rr2 * rh;
                float e   = __expf(2.0f * pre);
                float th  = 1.0f - 2.0f / (e + 1.0f);
                float hp  = bf2f(Hb[(size_t)row * 1024 + col]);
                out[(size_t)row * 1024 + col] = z * hp + (1.0f - z) * th;
            }
        }
    }
}

// ---------------- fallback (round-1, fp32 inline-convert) ----------------
#define KP 40
#define FBK 32
__global__ __launch_bounds__(256, 2)
void gru_fused_kernel(const float* __restrict__ X, const float* __restrict__ H,
                      const float* __restrict__ W, const float* __restrict__ R,
                      const float* __restrict__ bias, float* __restrict__ out)
{
    __shared__ __attribute__((aligned(16))) unsigned short ldsA[2][M_TILE * KP];
    __shared__ __attribute__((aligned(16))) unsigned short ldsW[6][N_TILE * KP];
    const int tid = threadIdx.x, bid = blockIdx.x;
    const int bn = bid & 15, bm = bid >> 4;
    const int m0 = bm * M_TILE, n0 = bn * N_TILE;
    const int wid = tid >> 6, lane = tid & 63;
    const int wr = wid >> 1, wc = wid & 1;
    const int lo = lane & 15, quad = lane >> 4;
    floatx4 acc_z[4][2] = {}, acc_r[4][2] = {}, acc_xh[4][2] = {}, acc_rh[4][2] = {};
    for (int k0 = 0; k0 < 1024; k0 += FBK) {
        #pragma unroll
        for (int i = 0; i < 8; ++i) {
            int idx = tid + i * 256;
            const float* base = (idx < 1024) ? X : H;
            int rem = idx & 1023, row = rem >> 3, kq = rem & 7;
            const float4 v = *(const float4*)(base + (size_t)(m0 + row) * 1024 + k0 + kq * 4);
            ushort4 s; s.x = f2bf(v.x); s.y = f2bf(v.y); s.z = f2bf(v.z); s.w = f2bf(v.w);
            *(ushort4*)&ldsA[idx >> 10][row * KP + kq * 4] = s;
        }
        #pragma unroll
        for (int i = 0; i < 3; ++i) {
            int b = tid + i * 256, g = b >> 7, rem = b & 127, kb = rem >> 4, c4 = rem & 15;
            const float* wb = (g < 3) ? W : R;
            int gm = (g < 3) ? g : g - 3;
            const float* src = wb + (size_t)(k0 + kb * 4) * 3072 + gm * 1024 + n0 + c4 * 4;
            float4 r0 = *(const float4*)(src);
            float4 r1 = *(const float4*)(src + 3072);
            float4 r2 = *(const float4*)(src + 2 * 3072);
            float4 r3 = *(const float4*)(src + 3 * 3072);
            ushort4 s0, s1, s2, s3;
            s0.x=f2bf(r0.x); s0.y=f2bf(r1.x); s0.z=f2bf(r2.x); s0.w=f2bf(r3.x);
            s1.x=f2bf(r0.y); s1.y=f2bf(r1.y); s1.z=f2bf(r2.y); s1.w=f2bf(r3.y);
            s2.x=f2bf(r0.z); s2.y=f2bf(r1.z); s2.z=f2bf(r2.z); s2.w=f2bf(r3.z);
            s3.x=f2bf(r0.w); s3.y=f2bf(r1.w); s3.z=f2bf(r2.w); s3.w=f2bf(r3.w);
            unsigned short* dst = &ldsW[g][0];
            *(ushort4*)&dst[(c4*4+0)*KP + kb*4] = s0;
            *(ushort4*)&dst[(c4*4+1)*KP + kb*4] = s1;
            *(ushort4*)&dst[(c4*4+2)*KP + kb*4] = s2;
            *(ushort4*)&dst[(c4*4+3)*KP + kb*4] = s3;
        }
        __syncthreads();
        shortx8 a_in[4], a_h[4];
        #pragma unroll
        for (int i = 0; i < 4; ++i) {
            a_in[i] = *(const shortx8*)&ldsA[0][(wr*64 + i*16 + lo) * KP + quad*8];
            a_h[i]  = *(const shortx8*)&ldsA[1][(wr*64 + i*16 + lo) * KP + quad*8];
        }
        #pragma unroll
        for (int j = 0; j < 2; ++j) {
            const int nc = (wc*32 + j*16 + lo) * KP + quad*8;
            shortx8 bz  = *(const shortx8*)&ldsW[0][nc];
            shortx8 bre = *(const shortx8*)&ldsW[1][nc];
            shortx8 bh  = *(const shortx8*)&ldsW[2][nc];
            shortx8 rz  = *(const shortx8*)&ldsW[3][nc];
            shortx8 rre = *(const shortx8*)&ldsW[4][nc];
            shortx8 rh  = *(const shortx8*)&ldsW[5][nc];
            #pragma unroll
            for (int i = 0; i < 4; ++i) {
                acc_z[i][j]  = __builtin_amdgcn_mfma_f32_16x16x32_bf16(a_in[i], bz,  acc_z[i][j],  0, 0, 0);
                acc_z[i][j]  = __builtin_amdgcn_mfma_f32_16x16x32_bf16(a_h[i],  rz,  acc_z[i][j],  0, 0, 0);
                acc_r[i][j]  = __builtin_amdgcn_mfma_f32_16x16x32_bf16(a_in[i], bre, acc_r[i][j],  0, 0, 0);
                acc_r[i][j]  = __builtin_amdgcn_mfma_f32_16x16x32_bf16(a_h[i],  rre, acc_r[i][j],  0, 0, 0);
                acc_xh[i][j] = __builtin_amdgcn_mfma_f32_16x16x32_bf16(a_in[i], bh,  acc_xh[i][j], 0, 0, 0);
                acc_rh[i][j] = __builtin_amdgcn_mfma_f32_16x16x32_bf16(a_h[i],  rh,  acc_rh[i][j], 0, 0, 0);
            }
        }
        __syncthreads();
    }
    #pragma unroll
    for (int j = 0; j < 2; ++j) {
        const int col = n0 + wc*32 + j*16 + lo;
        const float bz  = bias[col]        + bias[3072 + col];
        const float brr = bias[1024 + col] + bias[4096 + col];
        const float b0h = bias[2048 + col];
        const float b1h = bias[5120 + col];
        #pragma unroll
        for (int i = 0; i < 4; ++i) {
            const int rowb = m0 + wr*64 + i*16 + quad*4;
            #pragma unroll
            for (int r = 0; r < 4; ++r) {
                const int row = rowb + r;
                float sz = acc_z[i][j][r]  + bz;
                float sr = acc_r[i][j][r]  + brr;
                float xh = acc_xh[i][j][r] + b0h;
                float rh = acc_rh[i][j][r] + b1h;
                float z   = fminf(fmaxf(0.2f * sz + 0.5f, 0.0f), 1.0f);
                float rr2 = fminf(fmaxf(0.2f * sr + 0.5f, 0.0f), 1.0f);
                float pre = xh + rr2 * rh;
                float e   = __expf(2.0f * pre);
                float th  = 1.0f - 2.0f / (e + 1.0f);
                float hp  = H[(size_t)row * 1024 + col];
                out[(size_t)row * 1024 + col] = z * hp + (1.0f - z) * th;
            }
        }
    }
}

extern "C" void kernel_launch(void* const* d_in, const int* in_sizes, int n_in,
                              void* d_out, int out_size, void* d_ws, size_t ws_size,
                              hipStream_t stream)
{
    const float* X    = (const float*)d_in[0];
    const float* H    = (const float*)d_in[1];
    const float* W    = (const float*)d_in[2];
    const float* R    = (const float*)d_in[3];
    const float* bias = (const float*)d_in[4];
    float* out = (float*)d_out;

    const size_t need = (size_t)(8192 * 1024) * 2 * 2 + (size_t)(3072 * 1024) * 2 * 2; // 46.1 MB
    if (ws_size >= need) {
        unsigned short* Xb = (unsigned short*)d_ws;
        unsigned short* Hb = Xb + (size_t)8192 * 1024;
        unsigned short* Wt = Hb + (size_t)8192 * 1024;
        unsigned short* Rt = Wt + (size_t)3072 * 1024;
        hipLaunchKernelGGL(prep_kernel, dim3(16384 + 1536), dim3(256), 0, stream,
                           X, H, W, R, Xb, Hb, Wt, Rt);
        hipLaunchKernelGGL(gru_mfma_kernel, dim3(1024), dim3(256), 0, stream,
                           Xb, Hb, Wt, Rt, bias, out);
    } else {
        hipLaunchKernelGGL(gru_fused_kernel, dim3(1024), dim3(256), 0, stream, X, H, W, R, bias, out);
    }
}